// Round 10
// baseline (253.482 us; speedup 1.0000x reference)
//
#include <hip/hip_runtime.h>

#define HID 128
#define BN_EPS 1e-5f
#define CHUNK 8
#define G1_GEMM_BLOCKS 512
#define G1_HIST_BLOCKS 1024

typedef __attribute__((ext_vector_type(8))) short bf16x8;
typedef __attribute__((ext_vector_type(4))) float f32x4;

__device__ __forceinline__ float bf2f(unsigned short u) {
  union { unsigned int i; float f; } c; c.i = ((unsigned int)u) << 16; return c.f;
}
__device__ __forceinline__ unsigned short f2bf(float f) {
  union { float f; unsigned int i; } c; c.f = f;
  unsigned int u = c.i;
  return (unsigned short)((u + 0x7FFFu + ((u >> 16) & 1u)) >> 16);
}
__device__ __forceinline__ void unpack8(uint4 u, float* f) {
  f[0] = bf2f((unsigned short)(u.x & 0xffffu)); f[1] = bf2f((unsigned short)(u.x >> 16));
  f[2] = bf2f((unsigned short)(u.y & 0xffffu)); f[3] = bf2f((unsigned short)(u.y >> 16));
  f[4] = bf2f((unsigned short)(u.z & 0xffffu)); f[5] = bf2f((unsigned short)(u.z >> 16));
  f[6] = bf2f((unsigned short)(u.w & 0xffffu)); f[7] = bf2f((unsigned short)(u.w >> 16));
}

__global__ __launch_bounds__(256) void k_norm(const int* __restrict__ deg,
                                              float* __restrict__ nsnd, int total) {
  int i = blockIdx.x * blockDim.x + threadIdx.x;
  if (i < total) nsnd[i] = rsqrtf(fmaxf((float)deg[i], 1.0f));
}

__global__ __launch_bounds__(256) void k_scan_part(const int* __restrict__ deg,
                                                   int* __restrict__ bsum, int n) {
  __shared__ int red[256];
  const int t = threadIdx.x;
  const int i = blockIdx.x * 256 + t;
  red[t] = (i < n) ? deg[i] : 0;
  __syncthreads();
  for (int off = 128; off > 0; off >>= 1) {
    if (t < off) red[t] += red[t + off];
    __syncthreads();
  }
  if (t == 0) bsum[blockIdx.x] = red[0];
}

__global__ __launch_bounds__(1024) void k_scan_mid(int* bsum, int nb) {
  __shared__ int l[1024];
  const int t = threadIdx.x;
  l[t] = (t < nb) ? bsum[t] : 0;
  __syncthreads();
  for (int off = 1; off < 1024; off <<= 1) {
    int v = l[t];
    int add = (t >= off) ? l[t - off] : 0;
    __syncthreads();
    l[t] = v + add;
    __syncthreads();
  }
  if (t < nb) bsum[t] = (t == 0) ? 0 : l[t - 1];
}

__global__ __launch_bounds__(256) void k_scan_out(const int* __restrict__ deg,
                                                  const int* __restrict__ bpre,
                                                  int* __restrict__ offsets,
                                                  int* __restrict__ cursor, int n) {
  __shared__ int l[256];
  const int t = threadIdx.x;
  const int i = blockIdx.x * 256 + t;
  const int v = (i < n) ? deg[i] : 0;
  l[t] = v;
  __syncthreads();
  for (int off = 1; off < 256; off <<= 1) {
    int x = l[t];
    int add = (t >= off) ? l[t - off] : 0;
    __syncthreads();
    l[t] = x + add;
    __syncthreads();
  }
  const int excl = bpre[blockIdx.x] + l[t] - v;
  if (i < n) {
    offsets[i] = excl;
    cursor[i] = excl;
    if (i == n - 1) offsets[n] = excl + v;
  }
}

__global__ __launch_bounds__(256) void k_fill(const int* __restrict__ src,
                                              const int* __restrict__ dst,
                                              int* cursor, int* __restrict__ csc, int E) {
  const int stride = gridDim.x * blockDim.x;
  for (int i = blockIdx.x * blockDim.x + threadIdx.x; i < E; i += stride) {
    int d = dst[i];
    int pos = atomicAdd(&cursor[d], 1);
    csc[pos] = src[i];
  }
}

__global__ __launch_bounds__(256) void k_prep_w(const float* __restrict__ W,
                                                unsigned short* __restrict__ Wt) {
  int id = blockIdx.x * 256 + threadIdx.x;
  if (id < HID * HID) {
    int nn = id >> 7, kk = id & 127;
    Wt[id] = f2bf(W[kk * HID + nn]);
  }
}

__global__ __launch_bounds__(128) void k_bnparams(const float* __restrict__ ST,
                                                  const float* __restrict__ gamma,
                                                  const float* __restrict__ beta,
                                                  float* __restrict__ PS,
                                                  float* __restrict__ PH, float invN) {
  const int t = threadIdx.x;
  float m = ST[t] * invN;
  float var = ST[HID + t] * invN - m * m;
  float sc = gamma[t] * rsqrtf(var + BN_EPS);
  PS[t] = sc;
  PH[t] = beta[t] - m * sc;
}

// ---------------- shared MFMA GEMM body --------------------------------------
// MODE 0: A = fp32 X (UNSCALED).  MODE 1: A = prelu(bf16 X * PS + PH) * ns[row].
template <int MODE>
__device__ __forceinline__ void gemm_body(const void* __restrict__ Xin,
                                          const unsigned short* __restrict__ Wt,
                                          const float* __restrict__ ns,
                                          const float* __restrict__ PS,
                                          const float* __restrict__ PH,
                                          const float* __restrict__ aslope,
                                          unsigned short* __restrict__ Gb, int n,
                                          int blk, int nblocks,
                                          unsigned short (*stile)[16 * 136]) {
  const int wib = threadIdx.x >> 6;
  const int lane = threadIdx.x & 63;
  const int c = lane & 15;
  const int g = lane >> 4;
  const int nrb = (n + 15) >> 4;
  const int nw = nblocks * 4;

  bf16x8 bfr[8][4];
#pragma unroll
  for (int ct = 0; ct < 8; ++ct)
#pragma unroll
    for (int kt = 0; kt < 4; ++kt)
      bfr[ct][kt] = *reinterpret_cast<const bf16x8*>(Wt + (ct * 16 + c) * HID + kt * 32 + g * 8);

  const float slope = (MODE == 1) ? aslope[0] : 0.f;

  for (int w = blk * 4 + wib; w < nrb; w += nw) {
    const int row0 = w * 16;
    int arow = row0 + c;
    if (arow > n - 1) arow = n - 1;
    bf16x8 afr[4];
    if (MODE == 0) {
      const float* X = (const float*)Xin;
#pragma unroll
      for (int kt = 0; kt < 4; ++kt) {
        const float* p = X + (size_t)arow * HID + kt * 32 + g * 8;
        float4 v0 = *reinterpret_cast<const float4*>(p);
        float4 v1 = *reinterpret_cast<const float4*>(p + 4);
        bf16x8 a;
        a[0] = (short)f2bf(v0.x); a[1] = (short)f2bf(v0.y);
        a[2] = (short)f2bf(v0.z); a[3] = (short)f2bf(v0.w);
        a[4] = (short)f2bf(v1.x); a[5] = (short)f2bf(v1.y);
        a[6] = (short)f2bf(v1.z); a[7] = (short)f2bf(v1.w);
        afr[kt] = a;
      }
    } else {
      const unsigned short* Xb = (const unsigned short*)Xin;
      const float sc = ns[arow];
#pragma unroll
      for (int kt = 0; kt < 4; ++kt) {
        const int k0 = kt * 32 + g * 8;
        uint4 u = *reinterpret_cast<const uint4*>(Xb + (size_t)arow * HID + k0);
        float f[8];
        unpack8(u, f);
        float4 s0 = *reinterpret_cast<const float4*>(PS + k0);
        float4 s1 = *reinterpret_cast<const float4*>(PS + k0 + 4);
        float4 h0 = *reinterpret_cast<const float4*>(PH + k0);
        float4 h1 = *reinterpret_cast<const float4*>(PH + k0 + 4);
        float t;
        t = fmaf(f[0], s0.x, h0.x); f[0] = (t >= 0.f ? t : slope * t) * sc;
        t = fmaf(f[1], s0.y, h0.y); f[1] = (t >= 0.f ? t : slope * t) * sc;
        t = fmaf(f[2], s0.z, h0.z); f[2] = (t >= 0.f ? t : slope * t) * sc;
        t = fmaf(f[3], s0.w, h0.w); f[3] = (t >= 0.f ? t : slope * t) * sc;
        t = fmaf(f[4], s1.x, h1.x); f[4] = (t >= 0.f ? t : slope * t) * sc;
        t = fmaf(f[5], s1.y, h1.y); f[5] = (t >= 0.f ? t : slope * t) * sc;
        t = fmaf(f[6], s1.z, h1.z); f[6] = (t >= 0.f ? t : slope * t) * sc;
        t = fmaf(f[7], s1.w, h1.w); f[7] = (t >= 0.f ? t : slope * t) * sc;
        bf16x8 a;
        a[0] = (short)f2bf(f[0]); a[1] = (short)f2bf(f[1]);
        a[2] = (short)f2bf(f[2]); a[3] = (short)f2bf(f[3]);
        a[4] = (short)f2bf(f[4]); a[5] = (short)f2bf(f[5]);
        a[6] = (short)f2bf(f[6]); a[7] = (short)f2bf(f[7]);
        afr[kt] = a;
      }
    }

    f32x4 acc[8];
#pragma unroll
    for (int ct = 0; ct < 8; ++ct) acc[ct] = (f32x4){0.f, 0.f, 0.f, 0.f};
#pragma unroll
    for (int kt = 0; kt < 4; ++kt)
#pragma unroll
      for (int ct = 0; ct < 8; ++ct)
        acc[ct] = __builtin_amdgcn_mfma_f32_16x16x32_bf16(afr[kt], bfr[ct][kt], acc[ct], 0, 0, 0);

#pragma unroll
    for (int ct = 0; ct < 8; ++ct)
#pragma unroll
      for (int q = 0; q < 4; ++q)
        stile[wib][(g * 4 + q) * 136 + ct * 16 + c] = f2bf(acc[ct][q]);

#pragma unroll
    for (int p = 0; p < 4; ++p) {
      int rl = p * 4 + g;
      int grow = row0 + rl;
      if (grow < n) {
        uint4 v = *reinterpret_cast<const uint4*>(&stile[wib][rl * 136 + c * 8]);
        *reinterpret_cast<uint4*>(Gb + (size_t)grow * HID + c * 8) = v;
      }
    }
  }
}

// ---------------- fused: GEMM-1 (unscaled) || degree histogram ---------------
__global__ __launch_bounds__(256) void k_gemm1_hist(const float* __restrict__ X,
                                                    const unsigned short* __restrict__ Wt,
                                                    unsigned short* __restrict__ Gb, int n,
                                                    const int* __restrict__ src,
                                                    const int* __restrict__ dst,
                                                    int* deg, int E, int N) {
  __shared__ __align__(16) unsigned short stile[4][16 * 136];
  if (blockIdx.x >= G1_GEMM_BLOCKS) {
    const int stride = G1_HIST_BLOCKS * 256;
    for (int i = (blockIdx.x - G1_GEMM_BLOCKS) * 256 + threadIdx.x; i < E; i += stride) {
      atomicAdd(&deg[src[i]], 1);
      atomicAdd(&deg[N + dst[i]], 1);
    }
    return;
  }
  gemm_body<0>(X, Wt, nullptr, nullptr, nullptr, nullptr, Gb, n, blockIdx.x,
               G1_GEMM_BLOCKS, stile);
}

template <int MODE>
__global__ __launch_bounds__(256) void k_gemm_mfma(const void* __restrict__ Xin,
                                                   const unsigned short* __restrict__ Wt,
                                                   const float* __restrict__ ns,
                                                   const float* __restrict__ PS,
                                                   const float* __restrict__ PH,
                                                   const float* __restrict__ aslope,
                                                   unsigned short* __restrict__ Gb, int n) {
  __shared__ __align__(16) unsigned short stile[4][16 * 136];
  gemm_body<MODE>(Xin, Wt, ns, PS, PH, aslope, Gb, n, blockIdx.x, gridDim.x, stile);
}

// ---------------- gather-aggregate + stats, 4 rows/slot ----------------------
// NSMODE 1: multiply each gathered row by ns[srcidx] (layer 1, since GEMM-1 ran
// unscaled). NSMODE 0: rows already pre-scaled (layer 2).
template <int NSMODE>
__global__ __launch_bounds__(256) void k_agg_finish(const unsigned short* __restrict__ H,
                                                    const int* __restrict__ offsets,
                                                    const int* __restrict__ csc,
                                                    const float* __restrict__ ns,
                                                    const float* __restrict__ nd,
                                                    const float* __restrict__ bias,
                                                    unsigned short* __restrict__ OUT,
                                                    float* stats, int n) {
  const int lane = threadIdx.x & 31;
  const int slot = threadIdx.x >> 5;
  const int rstride = gridDim.x * 32;
  const float4 bj = reinterpret_cast<const float4*>(bias)[lane];
  float4 s = {0.f, 0.f, 0.f, 0.f}, sq = {0.f, 0.f, 0.f, 0.f};

  for (int i0 = blockIdx.x * 32 + slot * 4; i0 < n; i0 += rstride) {
    int e0[4], len[4];
    int maxlen = 0;
#pragma unroll
    for (int r = 0; r < 4; ++r) {
      const int ir = min(i0 + r, n - 1);
      const int a = offsets[ir], b = offsets[ir + 1];
      e0[r] = a;
      len[r] = (i0 + r < n) ? (b - a) : 0;
      maxlen = max(maxlen, len[r]);
    }
    float4 acc[4];
#pragma unroll
    for (int r = 0; r < 4; ++r) acc[r] = (float4){0.f, 0.f, 0.f, 0.f};

    for (int e = 0; e < maxlen; e += CHUNK) {
      int idx[4][CHUNK];
#pragma unroll
      for (int r = 0; r < 4; ++r)
#pragma unroll
        for (int k = 0; k < CHUNK; ++k)
          idx[r][k] = csc[max(e0[r] + min(e + k, len[r] - 1), 0)];
      uint2 v[4][CHUNK];
      float w[4][CHUNK];
#pragma unroll
      for (int r = 0; r < 4; ++r)
#pragma unroll
        for (int k = 0; k < CHUNK; ++k) {
          v[r][k] = *reinterpret_cast<const uint2*>(H + (size_t)idx[r][k] * HID + lane * 4);
          if (NSMODE) w[r][k] = ns[idx[r][k]];
        }
#pragma unroll
      for (int r = 0; r < 4; ++r)
#pragma unroll
        for (int k = 0; k < CHUNK; ++k) {
          if (e + k < len[r]) {
            const float wk = NSMODE ? w[r][k] : 1.0f;
            acc[r].x += bf2f((unsigned short)(v[r][k].x & 0xffffu)) * wk;
            acc[r].y += bf2f((unsigned short)(v[r][k].x >> 16)) * wk;
            acc[r].z += bf2f((unsigned short)(v[r][k].y & 0xffffu)) * wk;
            acc[r].w += bf2f((unsigned short)(v[r][k].y >> 16)) * wk;
          }
        }
    }
#pragma unroll
    for (int r = 0; r < 4; ++r) {
      if (i0 + r < n) {
        const float ndv = nd[i0 + r];
        float4 o;
        o.x = acc[r].x * ndv + bj.x;
        o.y = acc[r].y * ndv + bj.y;
        o.z = acc[r].z * ndv + bj.z;
        o.w = acc[r].w * ndv + bj.w;
        uint2 pk;
        pk.x = (unsigned int)f2bf(o.x) | ((unsigned int)f2bf(o.y) << 16);
        pk.y = (unsigned int)f2bf(o.z) | ((unsigned int)f2bf(o.w) << 16);
        *reinterpret_cast<uint2*>(OUT + (size_t)(i0 + r) * HID + lane * 4) = pk;
        s.x += o.x; s.y += o.y; s.z += o.z; s.w += o.w;
        sq.x += o.x * o.x; sq.y += o.y * o.y; sq.z += o.z * o.z; sq.w += o.w * o.w;
      }
    }
  }

  __shared__ float red[2][8][HID];
  *reinterpret_cast<float4*>(&red[0][slot][lane * 4]) = s;
  *reinterpret_cast<float4*>(&red[1][slot][lane * 4]) = sq;
  __syncthreads();
  const int t = threadIdx.x;
  if (t < HID) {
    float a = 0.f;
#pragma unroll
    for (int k = 0; k < 8; ++k) a += red[0][k][t];
    atomicAdd(&stats[t], a);
  } else {
    const int j = t - HID;
    float a = 0.f;
#pragma unroll
    for (int k = 0; k < 8; ++k) a += red[1][k][j];
    atomicAdd(&stats[HID + j], a);
  }
}

__global__ __launch_bounds__(256) void k_bn_final(const unsigned short* __restrict__ IN,
                                                  float* __restrict__ OUT,
                                                  const float* __restrict__ PS,
                                                  const float* __restrict__ PH,
                                                  const float* __restrict__ a, int total4) {
  const float slope = a[0];
  const int stride = gridDim.x * blockDim.x;
  for (int i = blockIdx.x * blockDim.x + threadIdx.x; i < total4; i += stride) {
    int j4 = i & 31;
    float4 ps = reinterpret_cast<const float4*>(PS)[j4];
    float4 ph = reinterpret_cast<const float4*>(PH)[j4];
    uint2 u = *reinterpret_cast<const uint2*>(IN + (size_t)i * 4);
    float4 o;
    float t;
    t = fmaf(bf2f((unsigned short)(u.x & 0xffffu)), ps.x, ph.x); o.x = t >= 0.f ? t : slope * t;
    t = fmaf(bf2f((unsigned short)(u.x >> 16)),     ps.y, ph.y); o.y = t >= 0.f ? t : slope * t;
    t = fmaf(bf2f((unsigned short)(u.y & 0xffffu)), ps.z, ph.z); o.z = t >= 0.f ? t : slope * t;
    t = fmaf(bf2f((unsigned short)(u.y >> 16)),     ps.w, ph.w); o.w = t >= 0.f ? t : slope * t;
    reinterpret_cast<float4*>(OUT)[i] = o;
  }
}

extern "C" void kernel_launch(void* const* d_in, const int* in_sizes, int n_in,
                              void* d_out, int out_size, void* d_ws, size_t ws_size,
                              hipStream_t stream) {
  const float* X   = (const float*)d_in[0];
  const float* W1  = (const float*)d_in[1];
  const float* b1  = (const float*)d_in[2];
  const float* g1  = (const float*)d_in[3];
  const float* be1 = (const float*)d_in[4];
  const float* a1  = (const float*)d_in[5];
  const float* W2  = (const float*)d_in[6];
  const float* b2  = (const float*)d_in[7];
  const float* g2  = (const float*)d_in[8];
  const float* be2 = (const float*)d_in[9];
  const float* a2  = (const float*)d_in[10];
  const int*   ei  = (const int*)d_in[11];

  const int N = in_sizes[0] / HID;
  const int E = in_sizes[11] / 2;
  const int* src = ei;
  const int* dst = ei + E;

  float* out = (float*)d_out;

  unsigned short* bufA = (unsigned short*)d_ws;
  unsigned short* bufB = bufA + (size_t)N * HID;
  int*   deg     = (int*)(bufB + (size_t)N * HID);
  float* NSND    = (float*)(deg + 2 * (size_t)N);
  float* ST      = NSND + 2 * (size_t)N;
  int*   offsets = (int*)(ST + 512);
  int*   csc     = offsets + N + 1;
  int*   bsum    = csc + E;
  unsigned short* Wt1 = (unsigned short*)(bsum + 1024);
  unsigned short* Wt2 = Wt1 + HID * HID;
  float* PS1 = (float*)(Wt2 + HID * HID);
  float* PH1 = PS1 + HID;
  float* PS2 = PH1 + HID;
  float* PH2 = PS2 + HID;
  int*   cursor  = deg;   // alias out-deg region (free after k_norm)

  const float invN = 1.0f / (float)N;
  const int nb = (N + 255) / 256;

  hipMemsetAsync(deg, 0, 2 * (size_t)N * sizeof(int), stream);
  hipMemsetAsync(ST, 0, 512 * sizeof(float), stream);

  k_prep_w<<<(HID * HID + 255) / 256, 256, 0, stream>>>(W1, Wt1);
  k_prep_w<<<(HID * HID + 255) / 256, 256, 0, stream>>>(W2, Wt2);

  // fused: GEMM-1 (unscaled X@W1) || degree histogram — independent work
  k_gemm1_hist<<<G1_GEMM_BLOCKS + G1_HIST_BLOCKS, 256, 0, stream>>>(
      X, Wt1, bufA, N, src, dst, deg, E, N);

  k_norm<<<(2 * N + 255) / 256, 256, 0, stream>>>(deg, NSND, 2 * N);
  k_scan_part<<<nb, 256, 0, stream>>>(deg + N, bsum, N);
  k_scan_mid<<<1, 1024, 0, stream>>>(bsum, nb);
  k_scan_out<<<nb, 256, 0, stream>>>(deg + N, bsum, offsets, cursor, N);
  k_fill<<<1024, 256, 0, stream>>>(src, dst, cursor, csc, E);

  // ---- layer 1: ns folded into aggregation (NSMODE=1) ----
  k_agg_finish<1><<<1024, 256, 0, stream>>>(bufA, offsets, csc, NSND, NSND + N, b1,
                                            bufB, ST, N);
  k_bnparams<<<1, 128, 0, stream>>>(ST, g1, be1, PS1, PH1, invN);

  // ---- layer 2 (BN1+PReLU1+ns fused into GEMM A-path) ----
  k_gemm_mfma<1><<<512, 256, 0, stream>>>(bufB, Wt2, NSND, PS1, PH1, a1, bufA, N);
  k_agg_finish<0><<<1024, 256, 0, stream>>>(bufA, offsets, csc, NSND, NSND + N, b2,
                                            bufB, ST + 256, N);
  k_bnparams<<<1, 128, 0, stream>>>(ST + 256, g2, be2, PS2, PH2, invN);
  k_bn_final<<<2048, 256, 0, stream>>>(bufB, out, PS2, PH2, a2, N * (HID / 4));
}